// Round 1
// baseline (310.983 us; speedup 1.0000x reference)
//
#include <hip/hip_runtime.h>
#include <math.h>

using f16   = _Float16;
using f16x4 = __attribute__((ext_vector_type(4))) _Float16;
using f16x8 = __attribute__((ext_vector_type(8))) _Float16;
using f32x4 = __attribute__((ext_vector_type(4))) float;

#define NW    343           // tokens per window (7*7*7)
#define NWP   352           // padded to 22*16
#define VTP   356           // V^T LDS pitch (keeps b64 frag reads 8B-aligned, spreads banks)
#define HEADS 8
#define DIM   256
#define MTOT  43904         // 128 windows * 343
#define LOG2E 1.4426950408889634f
#define QSC   (0.17677669529663687f * 1.4426950408889634f)  // dh^-0.5 * log2(e)

// ---------------- converts ----------------
__global__ void cvt_x(const float* __restrict__ x, f16* __restrict__ xb) {
    int id = blockIdx.x * 256 + threadIdx.x;   // 4 elems per thread, exact
    float4 v = *(const float4*)(x + id * 4);
    f16x4 o = { (f16)v.x, (f16)v.y, (f16)v.z, (f16)v.w };
    *(f16x4*)(xb + id * 4) = o;
}

// W (K=256 x N row-major) -> WT (N x 256), scale first scaleN output cols
__global__ void cvt_wT(const float* __restrict__ W, f16* __restrict__ WT,
                       int N, int scaleN, float sc) {
    int id = blockIdx.x * 256 + threadIdx.x;   // grid = N blocks, id < N*256
    int n = id >> 8, k = id & 255;
    float v = W[k * N + n];
    if (n < scaleN) v *= sc;
    WT[n * 256 + k] = (f16)v;
}

// padded bias: bp[h][i][j], i,j in [0,352); j>=343 -> -1e30 (mask), i>=343 -> 0
__global__ void bias_k(const float* __restrict__ tab, float* __restrict__ bp) {
    int id = blockIdx.x * 256 + threadIdx.x;   // 8*352*352 exact
    int h = id / (NWP * NWP);
    int rem = id - h * NWP * NWP;
    int i = rem / NWP, j = rem - (rem / NWP) * NWP;
    float v;
    if (j >= NW) v = -1e30f;
    else if (i >= NW) v = 0.f;
    else {
        int a1 = i / 49, a2 = (i / 7) % 7, a3 = i % 7;
        int b1 = j / 49, b2 = (j / 7) % 7, b3 = j % 7;
        int idx = (a1 - b1 + 6) * 169 + (a2 - b2 + 6) * 13 + (a3 - b3 + 6);
        v = tab[idx * 8 + h] * LOG2E;
    }
    bp[id] = v;
}

// ---------------- GEMM: C(M x N) = A(M x 256) * Bt(N x 256)^T, f16 in, f32 acc ----
template<bool OUT_F32>
__launch_bounds__(256)
__global__ void gemm_k(const f16* __restrict__ A, const f16* __restrict__ Bt,
                       void* __restrict__ Cp, int N) {
    __shared__ f16 As[64 * 32];
    __shared__ f16 Bs[64 * 32];
    const int m0 = blockIdx.x * 64;
    const int n0 = blockIdx.y * 64;
    const int t = threadIdx.x;
    const int wave = t >> 6, lane = t & 63;
    const int q = lane >> 4, c = lane & 15;
    const int wm = (wave >> 1) * 32, wn = (wave & 1) * 32;
    const int srow = t >> 2, sunit = t & 3;

    f32x4 acc[2][2] = {};
#pragma unroll
    for (int ks = 0; ks < 256; ks += 32) {
        *(uint4*)&As[srow * 32 + sunit * 8] =
            *(const uint4*)&A[(m0 + srow) * 256 + ks + sunit * 8];
        *(uint4*)&Bs[srow * 32 + sunit * 8] =
            *(const uint4*)&Bt[(n0 + srow) * 256 + ks + sunit * 8];
        __syncthreads();
        f16x8 af0 = *(const f16x8*)&As[(wm + c) * 32 + q * 8];
        f16x8 af1 = *(const f16x8*)&As[(wm + 16 + c) * 32 + q * 8];
        f16x8 bf0 = *(const f16x8*)&Bs[(wn + c) * 32 + q * 8];
        f16x8 bf1 = *(const f16x8*)&Bs[(wn + 16 + c) * 32 + q * 8];
        acc[0][0] = __builtin_amdgcn_mfma_f32_16x16x32_f16(af0, bf0, acc[0][0], 0, 0, 0);
        acc[0][1] = __builtin_amdgcn_mfma_f32_16x16x32_f16(af0, bf1, acc[0][1], 0, 0, 0);
        acc[1][0] = __builtin_amdgcn_mfma_f32_16x16x32_f16(af1, bf0, acc[1][0], 0, 0, 0);
        acc[1][1] = __builtin_amdgcn_mfma_f32_16x16x32_f16(af1, bf1, acc[1][1], 0, 0, 0);
        __syncthreads();
    }
#pragma unroll
    for (int a = 0; a < 2; a++)
#pragma unroll
        for (int b = 0; b < 2; b++) {
            int row0 = m0 + wm + a * 16 + q * 4;
            int col = n0 + wn + b * 16 + c;
#pragma unroll
            for (int r = 0; r < 4; r++) {
                float v = acc[a][b][r];
                if (OUT_F32) ((float*)Cp)[(size_t)(row0 + r) * N + col] = v;
                else         ((f16*)Cp)[(size_t)(row0 + r) * N + col] = (f16)v;
            }
        }
}

// ---------------- fused flash attention, 1 block = (window, head) ----------------
__launch_bounds__(256)
__global__ void attn_k(const f16* __restrict__ qkv, const float* __restrict__ biasP,
                       f16* __restrict__ ctx) {
    const int w = blockIdx.x >> 3;
    const int h = blockIdx.x & 7;
    __shared__ f16 Ks[NWP * 32];       // key-major [token][feat]
    __shared__ f16 Vt[32 * VTP];       // transposed [dh][token]
    const int t = threadIdx.x;
    const size_t base = (size_t)(w * NW) * 768;

    // stage K (raw 16B copies, zero-fill pad rows)
    for (int u = t; u < NWP * 4; u += 256) {
        int row = u >> 2, un = u & 3;
        uint4 val;
        if (row < NW) val = *(const uint4*)&qkv[base + (size_t)row * 768 + 256 + h * 32 + un * 8];
        else { val.x = val.y = val.z = val.w = 0u; }
        *(uint4*)&Ks[row * 32 + un * 8] = val;
    }
    // stage V transposed
    for (int u = t; u < NWP * 4; u += 256) {
        int row = u >> 2, un = u & 3;
        if (row < NW) {
            uint4 val = *(const uint4*)&qkv[base + (size_t)row * 768 + 512 + h * 32 + un * 8];
            const f16* pv = (const f16*)&val;
#pragma unroll
            for (int e = 0; e < 8; e++) Vt[(un * 8 + e) * VTP + row] = pv[e];
        } else {
#pragma unroll
            for (int e = 0; e < 8; e++) Vt[(un * 8 + e) * VTP + row] = (f16)0.f;
        }
    }
    __syncthreads();

    const int wave = t >> 6, lane = t & 63;
    const int q = lane >> 4, c = lane & 15;
    const float* biasH = biasP + (size_t)h * NWP * NWP;

    for (int qt = wave; qt < NWP / 16; qt += 4) {
        const int iq = qt * 16 + c;                 // query owned by this lane (col axis)
        const int iqc = iq < NW ? iq : NW - 1;      // clamp loads for pad queries
        // Q fragment (pre-scaled by dh^-0.5*log2e via weight transform)
        f16x8 qf = *(const f16x8*)&qkv[base + (size_t)iqc * 768 + h * 32 + q * 8];
        const float* brow = biasH + (size_t)iq * NWP;
        f32x4 o0 = {0.f, 0.f, 0.f, 0.f}, o1 = {0.f, 0.f, 0.f, 0.f};
        float m_run = -3.0e38f, l_run = 0.f;

        for (int jt = 0; jt < NWP / 16; jt++) {
            const int jb = jt * 16;
            // S^T = K * Q^T : rows = keys (reg axis), cols = queries (lane axis)
            f16x8 kf = *(const f16x8*)&Ks[(jb + c) * 32 + q * 8];
            f32x4 z = {0.f, 0.f, 0.f, 0.f};
            f32x4 s = __builtin_amdgcn_mfma_f32_16x16x32_f16(kf, qf, z, 0, 0, 0);
            // logits (base-2 domain); pad cols masked via bias = -1e30
            f32x4 b4 = *(const f32x4*)&brow[jb + q * 4];
            float l0 = s[0] + b4[0], l1 = s[1] + b4[1];
            float l2 = s[2] + b4[2], l3 = s[3] + b4[3];
            float mx = fmaxf(fmaxf(l0, l1), fmaxf(l2, l3));
            mx = fmaxf(mx, __shfl_xor(mx, 16));
            mx = fmaxf(mx, __shfl_xor(mx, 32));
            float m_new = fmaxf(m_run, mx);
            float alpha = exp2f(m_run - m_new);
            float p0 = exp2f(l0 - m_new), p1 = exp2f(l1 - m_new);
            float p2 = exp2f(l2 - m_new), p3 = exp2f(l3 - m_new);
            float ps = p0 + p1 + p2 + p3;
            ps += __shfl_xor(ps, 16);
            ps += __shfl_xor(ps, 32);
            l_run = l_run * alpha + ps;
            m_run = m_new;
#pragma unroll
            for (int r = 0; r < 4; r++) { o0[r] *= alpha; o1[r] *= alpha; }
            // P regs are already B-operand layout of P^T for 16x16x16: O^T += V^T * P^T
            f16x4 pf = { (f16)p0, (f16)p1, (f16)p2, (f16)p3 };
            f16x4 v0 = *(const f16x4*)&Vt[c * VTP + jb + q * 4];
            f16x4 v1 = *(const f16x4*)&Vt[(16 + c) * VTP + jb + q * 4];
            o0 = __builtin_amdgcn_mfma_f32_16x16x16f16(v0, pf, o0, 0, 0, 0);
            o1 = __builtin_amdgcn_mfma_f32_16x16x16f16(v1, pf, o1, 0, 0, 0);
        }
        if (iq < NW) {
            float inv = 1.f / l_run;
            size_t ob = (size_t)(w * NW + iq) * 256 + h * 32;
            f16x4 s0 = { (f16)(o0[0] * inv), (f16)(o0[1] * inv),
                         (f16)(o0[2] * inv), (f16)(o0[3] * inv) };
            f16x4 s1 = { (f16)(o1[0] * inv), (f16)(o1[1] * inv),
                         (f16)(o1[2] * inv), (f16)(o1[3] * inv) };
            *(f16x4*)&ctx[ob + q * 4] = s0;        // dh = q*4..q*4+3
            *(f16x4*)&ctx[ob + 16 + q * 4] = s1;   // dh = 16+q*4..
        }
    }
}

// ---------------- launch ----------------
extern "C" void kernel_launch(void* const* d_in, const int* in_sizes, int n_in,
                              void* d_out, int out_size, void* d_ws, size_t ws_size,
                              hipStream_t stream) {
    const float* x    = (const float*)d_in[0];
    const float* wqkv = (const float*)d_in[1];
    const float* wout = (const float*)d_in[2];
    const float* tab  = (const float*)d_in[3];

    char* ws = (char*)d_ws;
    size_t off = 0;
    f16*   xb     = (f16*)(ws + off);   off += (size_t)MTOT * 256 * 2;       // 22.5 MB
    f16*   wqkvT  = (f16*)(ws + off);   off += (size_t)768 * 256 * 2;
    f16*   woutT  = (f16*)(ws + off);   off += (size_t)256 * 256 * 2;
    float* biasP  = (float*)(ws + off); off += (size_t)8 * NWP * NWP * 4;    // 4 MB
    f16*   qkvb   = (f16*)(ws + off);   off += (size_t)MTOT * 768 * 2;       // 67.4 MB
    f16*   ctxb   = (f16*)(ws + off);   off += (size_t)MTOT * 256 * 2;       // 22.5 MB
    if (ws_size < off) return;  // insufficient scratch -> visible failure, no OOB

    cvt_x <<<MTOT * 256 / 1024, 256, 0, stream>>>(x, xb);
    cvt_wT<<<768, 256, 0, stream>>>(wqkv, wqkvT, 768, 256, QSC);
    cvt_wT<<<256, 256, 0, stream>>>(wout, woutT, 256, 0, 1.f);
    bias_k<<<8 * NWP * NWP / 256, 256, 0, stream>>>(tab, biasP);
    gemm_k<false><<<dim3(MTOT / 64, 768 / 64), 256, 0, stream>>>(xb, wqkvT, qkvb, 768);
    attn_k<<<128 * HEADS, 256, 0, stream>>>(qkvb, biasP, ctxb);
    gemm_k<true><<<dim3(MTOT / 64, 256 / 64), 256, 0, stream>>>(ctxb, woutT, d_out, 256);
}